// Round 2
// baseline (148.470 us; speedup 1.0000x reference)
//
#include <hip/hip_runtime.h>

#define B_ 512
#define L_ 8192
#define N_ 128
#define S_ 256
#define DELIM_ 5
#define T_ 1024          // 16 waves/block
#define NW_ (T_ / 64)

typedef int   __attribute__((ext_vector_type(4))) i32x4;
typedef float __attribute__((ext_vector_type(4))) f32x4;

// One block per row.
// Phase 1: coalesced nontemporal int4 row read -> registers AND swizzled LDS
//          (ds_write_b128 with in-register component permute); packed block
//          scan -> ordered delimiter positions -> chunk table.
// Phase 2: one sentence per wave per iteration; element layout e = 4*lane + j,
//          branchless clamped LDS gather (no exec-mask toggles), otp/mask go
//          out as NONTEMPORAL global_store_dwordx4 (write-once streams; avoid
//          L2 allocate churn — the harness fill sustains 6.6 TB/s this way).
//          ballot+popc for len_sent. No atomics.
//
// Swizzle: token at logical position p lives at LDS word  p ^ ((p>>5)&3).
//  - XOR value < 4 and 4-aligned groups => permutation stays inside each
//    aligned 4-word group => phase-1 int4 writes stay b128 (components permuted).
//  - Phase-2 read p = start + 4*lane + j (j fixed): lanes l and l+32 alias a
//    bank, all others distinct => 2-way conflict = free (m136).
__device__ __forceinline__ int sw_idx(int p) { return p ^ ((p >> 5) & 3); }

__global__ __launch_bounds__(T_, 8) void split_kernel(const int* __restrict__ x,
                                                      float* __restrict__ otp,
                                                      float* __restrict__ len_doc,
                                                      float* __restrict__ mask) {
    const int b = blockIdx.x;
    const int t = threadIdx.x;
    const int lane = t & 63;
    const int w = t >> 6;
    const int* __restrict__ row = x + (size_t)b * L_;

    __shared__ __align__(16) int s_row[L_ + 1];  // swizzled row + trailing DELIM
    __shared__ int s_wsum[NW_];
    __shared__ int s_dpos[N_ - 1];  // first 127 delimiter positions (tail merge)
    __shared__ int s_start[N_];
    __shared__ int s_cl[N_];        // copy length: 0 for empty/unused, else min(size, S)
    __shared__ int s_doc[NW_];

    // ---- phase 1a: coalesced nt int4 loads; stage into swizzled LDS ----
    const i32x4 r0 = __builtin_nontemporal_load((const i32x4*)row + t);       // [4t, 4t+4)
    const i32x4 r1 = __builtin_nontemporal_load((const i32x4*)row + t + T_);  // [4096+4t, ...)

    // word 4t+j must hold token 4t+(j^v)  =>  w[j] = r[j^v]
    const int v = (t >> 3) & 3;                   // same for t and t+T_ (T_/8 % 4 == 0)
    i32x4 w0 = r0, w1 = r1;
    if (v == 1)      { w0 = r0.yxwz; w1 = r1.yxwz; }
    else if (v == 2) { w0 = r0.zwxy; w1 = r1.zwxy; }
    else if (v == 3) { w0 = r0.wzyx; w1 = r1.wzyx; }
    ((i32x4*)s_row)[t] = w0;                      // ds_write_b128, conflict-free
    ((i32x4*)s_row)[t + T_] = w1;
    if (t == 0) s_row[L_] = DELIM_;               // rpad[L]; sw_idx(L_) == L_

    const int c0 = (r0.x == DELIM_) + (r0.y == DELIM_) + (r0.z == DELIM_) + (r0.w == DELIM_);
    const int c1 = (r1.x == DELIM_) + (r1.y == DELIM_) + (r1.z == DELIM_) + (r1.w == DELIM_);
    const int packed = c0 | (c1 << 16);

    // wave inclusive scan of packed counts
    int sv = packed;
#pragma unroll
    for (int d = 1; d < 64; d <<= 1) {
        int n = __shfl_up(sv, d, 64);
        if (lane >= d) sv += n;
    }
    if (lane == 63) s_wsum[w] = sv;
    __syncthreads();

    int woff = 0, tot = 0;
#pragma unroll
    for (int i = 0; i < NW_; ++i) {
        const int s = s_wsum[i];
        if (i < w) woff += s;
        tot += s;
    }
    const int pre = woff + sv - packed;         // exclusive prefix (packed)
    const int c0tot = tot & 0xffff;             // total delims in first half
    const int m = c0tot + (tot >> 16);          // total delims in row
    const int off0 = pre & 0xffff;
    const int off1 = c0tot + (pre >> 16);

    // ---- phase 1b: emit ordered delimiter positions from registers ----
    if (c0 > 0 && off0 < N_ - 1) {
        int o = off0;
        const int p = 4 * t;
        if (r0.x == DELIM_) { if (o < N_ - 1) s_dpos[o] = p;     ++o; }
        if (r0.y == DELIM_) { if (o < N_ - 1) s_dpos[o] = p + 1; ++o; }
        if (r0.z == DELIM_) { if (o < N_ - 1) s_dpos[o] = p + 2; ++o; }
        if (r0.w == DELIM_) { if (o < N_ - 1) s_dpos[o] = p + 3; ++o; }
    }
    if (c1 > 0 && off1 < N_ - 1) {
        int o = off1;
        const int p = 4 * T_ + 4 * t;
        if (r1.x == DELIM_) { if (o < N_ - 1) s_dpos[o] = p;     ++o; }
        if (r1.y == DELIM_) { if (o < N_ - 1) s_dpos[o] = p + 1; ++o; }
        if (r1.z == DELIM_) { if (o < N_ - 1) s_dpos[o] = p + 2; ++o; }
        if (r1.w == DELIM_) { if (o < N_ - 1) s_dpos[o] = p + 3; ++o; }
    }
    __syncthreads();

    // ---- phase 1c: chunk table ----
    if (t < N_) {
        const int k = t;
        const int mc = (m < N_ - 1) ? m : (N_ - 1);  // last used chunk index
        int start = 0, cl = 0;
        if (k <= mc) {
            start = (k == 0) ? 0 : (s_dpos[k - 1] + 1);
            const int end = (k < mc) ? s_dpos[k] : L_;  // rpad[L] = trailing DELIM
            const int size = end - start + 1;           // delimiter belongs to its chunk
            cl = (size <= 1) ? 0 : (size < S_ ? size : S_);  // lone delim -> all PAD
        }
        s_start[k] = start;
        s_cl[k] = cl;
    }
    __syncthreads();

    // ---- phase 2: wave w handles sentence k = i*NW_ + w (8 iterations) ----
    float* __restrict__ otp_b = otp + (size_t)b * N_ * S_;
    float* __restrict__ msk_b = mask + (size_t)b * N_ * S_;
    int doccnt = 0;
    const int e0 = lane << 2;                     // this lane's 4 contiguous elements
#pragma unroll
    for (int i = 0; i < (N_ / NW_); ++i) {
        const int k = i * NW_ + w;
        const int start = s_start[k];  // wave-uniform LDS broadcast
        const int cl = s_cl[k];
        f32x4 tf = {0.f, 0.f, 0.f, 0.f};
        f32x4 mk = {0.f, 0.f, 0.f, 0.f};
        int len = 0;
        if (cl > 0) {                  // wave-uniform: skip empty/unused chunks
            const int cm = cl - 1;     // clamp target; start+cm <= L_ always
            // branchless clamped gather: unconditional ds_read + cndmask select
            int t0 = s_row[sw_idx(start + (e0 + 0 <= cm ? e0 + 0 : cm))];
            int t1 = s_row[sw_idx(start + (e0 + 1 <= cm ? e0 + 1 : cm))];
            int t2 = s_row[sw_idx(start + (e0 + 2 <= cm ? e0 + 2 : cm))];
            int t3 = s_row[sw_idx(start + (e0 + 3 <= cm ? e0 + 3 : cm))];
            t0 = (e0 + 0 < cl) ? t0 : 0;
            t1 = (e0 + 1 < cl) ? t1 : 0;
            t2 = (e0 + 2 < cl) ? t2 : 0;
            t3 = (e0 + 3 < cl) ? t3 : 0;
            len += __popcll(__ballot(t0 != 0));   // wave-uniform nonzero count
            len += __popcll(__ballot(t1 != 0));
            len += __popcll(__ballot(t2 != 0));
            len += __popcll(__ballot(t3 != 0));
            tf.x = (float)t0; tf.y = (float)t1; tf.z = (float)t2; tf.w = (float)t3;
            mk.x = e0 + 0 < len ? 1.f : 0.f;
            mk.y = e0 + 1 < len ? 1.f : 0.f;
            mk.z = e0 + 2 < len ? 1.f : 0.f;
            mk.w = e0 + 3 < len ? 1.f : 0.f;
        }
        // write-once streams: nontemporal global_store_dwordx4
        __builtin_nontemporal_store(tf, (f32x4*)(otp_b + (size_t)k * S_) + lane);
        __builtin_nontemporal_store(mk, (f32x4*)(msk_b + (size_t)k * S_) + lane);
        doccnt += (len > 0);
    }

    // ---- len_doc: one LDS reduction per block, no atomics ----
    if (lane == 0) s_doc[w] = doccnt;
    __syncthreads();
    if (t == 0) {
        int d = 0;
#pragma unroll
        for (int i = 0; i < NW_; ++i) d += s_doc[i];
        len_doc[b] = (float)d;
    }
}

extern "C" void kernel_launch(void* const* d_in, const int* in_sizes, int n_in,
                              void* d_out, int out_size, void* d_ws, size_t ws_size,
                              hipStream_t stream) {
    const int* x = (const int*)d_in[0];
    float* out = (float*)d_out;

    // d_out layout (flat, return order): otp[B*N*S] | len_doc[B] | mask[B*N*S]
    float* otp = out;
    float* len_doc = out + (size_t)B_ * N_ * S_;
    float* mask = len_doc + B_;

    split_kernel<<<B_, T_, 0, stream>>>(x, otp, len_doc, mask);
}

// Round 3
// 146.242 us; speedup vs baseline: 1.0152x; 1.0152x over previous
//
#include <hip/hip_runtime.h>

#define B_ 512
#define L_ 8192
#define N_ 128
#define S_ 256
#define DELIM_ 5
#define TA_ 1024         // table kernel: 16 waves/block, one block per row
#define NWA_ (TA_ / 64)
#define TB_ 256          // writer kernel: fill-shaped lean blocks

// ---------------------------------------------------------------------------
// Kernel A: per-row delimiter scan -> chunk table {start, cl} in workspace.
// No LDS row staging (delimiter positions are emitted from registers).
// Also zeroes len_doc[b] so the writer can accumulate atomically.
// ---------------------------------------------------------------------------
__global__ __launch_bounds__(TA_) void table_kernel(const int* __restrict__ x,
                                                    int2* __restrict__ tbl,
                                                    float* __restrict__ len_doc) {
    const int b = blockIdx.x;
    const int t = threadIdx.x;
    const int lane = t & 63;
    const int w = t >> 6;
    const int* __restrict__ row = x + (size_t)b * L_;

    __shared__ int s_wsum[NWA_];
    __shared__ int s_dpos[N_ - 1];  // first 127 delimiter positions (tail merge)

    const int4 r0 = ((const int4*)row)[t];        // tokens [4t, 4t+4)
    const int4 r1 = ((const int4*)row)[t + TA_];  // tokens [4096+4t, ...)

    const int c0 = (r0.x == DELIM_) + (r0.y == DELIM_) + (r0.z == DELIM_) + (r0.w == DELIM_);
    const int c1 = (r1.x == DELIM_) + (r1.y == DELIM_) + (r1.z == DELIM_) + (r1.w == DELIM_);
    const int packed = c0 | (c1 << 16);

    // wave inclusive scan of packed counts
    int sv = packed;
#pragma unroll
    for (int d = 1; d < 64; d <<= 1) {
        int n = __shfl_up(sv, d, 64);
        if (lane >= d) sv += n;
    }
    if (lane == 63) s_wsum[w] = sv;
    __syncthreads();

    int woff = 0, tot = 0;
#pragma unroll
    for (int i = 0; i < NWA_; ++i) {
        const int s = s_wsum[i];
        if (i < w) woff += s;
        tot += s;
    }
    const int pre = woff + sv - packed;         // exclusive prefix (packed)
    const int c0tot = tot & 0xffff;             // total delims in first half
    const int m = c0tot + (tot >> 16);          // total delims in row
    const int off0 = pre & 0xffff;
    const int off1 = c0tot + (pre >> 16);

    // ordered delimiter positions from registers
    if (c0 > 0 && off0 < N_ - 1) {
        int o = off0;
        const int p = 4 * t;
        if (r0.x == DELIM_) { if (o < N_ - 1) s_dpos[o] = p;     ++o; }
        if (r0.y == DELIM_) { if (o < N_ - 1) s_dpos[o] = p + 1; ++o; }
        if (r0.z == DELIM_) { if (o < N_ - 1) s_dpos[o] = p + 2; ++o; }
        if (r0.w == DELIM_) { if (o < N_ - 1) s_dpos[o] = p + 3; ++o; }
    }
    if (c1 > 0 && off1 < N_ - 1) {
        int o = off1;
        const int p = 4 * TA_ + 4 * t;
        if (r1.x == DELIM_) { if (o < N_ - 1) s_dpos[o] = p;     ++o; }
        if (r1.y == DELIM_) { if (o < N_ - 1) s_dpos[o] = p + 1; ++o; }
        if (r1.z == DELIM_) { if (o < N_ - 1) s_dpos[o] = p + 2; ++o; }
        if (r1.w == DELIM_) { if (o < N_ - 1) s_dpos[o] = p + 3; ++o; }
    }
    __syncthreads();

    // chunk table
    if (t < N_) {
        const int k = t;
        const int mc = (m < N_ - 1) ? m : (N_ - 1);  // last used chunk index
        int start = 0, cl = 0;
        if (k <= mc) {
            start = (k == 0) ? 0 : (s_dpos[k - 1] + 1);
            const int end = (k < mc) ? s_dpos[k] : L_;  // virtual rpad[L] = DELIM
            const int size = end - start + 1;           // delimiter belongs to its chunk
            cl = (size <= 1) ? 0 : (size < S_ ? size : S_);  // lone delim -> all PAD
        }
        tbl[b * N_ + k] = make_int2(start, cl);
    }
    if (t == 0) len_doc[b] = 0.0f;
}

// ---------------------------------------------------------------------------
// Kernel B: barrier-free, LDS-free streaming writer. dim3 grid(8, B_),
// 256 threads (4 waves); each wave handles 4 sentences. Tokens gathered
// directly from global (x is 16.8 MB -> LLC-resident after kernel A).
// Element layout e = 64*j + lane: every load/store is a coalesced 256 B
// dword op. len_sent via ballot+popc; len_doc via one atomicAdd per block.
// ---------------------------------------------------------------------------
__global__ __launch_bounds__(TB_, 8) void write_kernel(const int* __restrict__ x,
                                                       const int2* __restrict__ tbl,
                                                       float* __restrict__ otp,
                                                       float* __restrict__ len_doc,
                                                       float* __restrict__ mask) {
    const int kb = blockIdx.x;   // 0..7: which group of 16 sentences
    const int b  = blockIdx.y;   // row
    const int t = threadIdx.x;
    const int lane = t & 63;
    const int w = t >> 6;
    const int* __restrict__ row = x + (size_t)b * L_;
    float* __restrict__ otp_b = otp + (size_t)b * N_ * S_;
    float* __restrict__ msk_b = mask + (size_t)b * N_ * S_;
    __shared__ int s_cnt[TB_ / 64];

    int cnt = 0;
#pragma unroll
    for (int i = 0; i < 4; ++i) {
        const int k = kb * 16 + w * 4 + i;
        const int2 sc = tbl[b * N_ + k];   // wave-uniform broadcast load
        const int start = sc.x, cl = sc.y;
        int tok0 = 0, tok1 = 0, tok2 = 0, tok3 = 0;
        int len = 0;
        if (cl > 0) {                      // wave-uniform: skip empty/unused
            // branchless clamped gather; virtual trailing delimiter at idx==L_
#pragma unroll
            for (int j = 0; j < 4; ++j) {
                const int e = 64 * j + lane;
                const int idx = start + e;
                const int a = (idx < L_) ? idx : (L_ - 1);  // stay in-bounds
                int v = row[a];                              // coalesced 256 B
                v = (idx == L_) ? DELIM_ : v;
                v = (e < cl) ? v : 0;
                if (j == 0) tok0 = v; else if (j == 1) tok1 = v;
                else if (j == 2) tok2 = v; else tok3 = v;
            }
            len += __popcll(__ballot(tok0 != 0));
            len += __popcll(__ballot(tok1 != 0));
            len += __popcll(__ballot(tok2 != 0));
            len += __popcll(__ballot(tok3 != 0));
        }
        // stores unconditional: cl==0 sentences must emit zeros too
        {
            const int e0 = lane;
            otp_b[(size_t)k * S_ + e0]       = (float)tok0;
            otp_b[(size_t)k * S_ + e0 + 64]  = (float)tok1;
            otp_b[(size_t)k * S_ + e0 + 128] = (float)tok2;
            otp_b[(size_t)k * S_ + e0 + 192] = (float)tok3;
            msk_b[(size_t)k * S_ + e0]       = (e0       < len) ? 1.0f : 0.0f;
            msk_b[(size_t)k * S_ + e0 + 64]  = (e0 + 64  < len) ? 1.0f : 0.0f;
            msk_b[(size_t)k * S_ + e0 + 128] = (e0 + 128 < len) ? 1.0f : 0.0f;
            msk_b[(size_t)k * S_ + e0 + 192] = (e0 + 192 < len) ? 1.0f : 0.0f;
        }
        cnt += (len > 0);
    }
    if (lane == 0) s_cnt[w] = cnt;
    __syncthreads();
    if (t == 0) {
        int d = 0;
#pragma unroll
        for (int i = 0; i < TB_ / 64; ++i) d += s_cnt[i];
        if (d) atomicAdd(&len_doc[b], (float)d);
    }
}

// ---------------------------------------------------------------------------
// Fallback: proven monolithic kernel (R1 version, normal stores) in case the
// workspace is too small for the chunk table.
// ---------------------------------------------------------------------------
__device__ __forceinline__ int sw_idx(int p) { return p ^ ((p >> 5) & 3); }

__global__ __launch_bounds__(TA_, 8) void split_kernel(const int* __restrict__ x,
                                                       float* __restrict__ otp,
                                                       float* __restrict__ len_doc,
                                                       float* __restrict__ mask) {
    const int b = blockIdx.x;
    const int t = threadIdx.x;
    const int lane = t & 63;
    const int w = t >> 6;
    const int* __restrict__ row = x + (size_t)b * L_;

    __shared__ __align__(16) int s_row[L_ + 1];
    __shared__ int s_wsum[NWA_];
    __shared__ int s_dpos[N_ - 1];
    __shared__ int s_start[N_];
    __shared__ int s_cl[N_];
    __shared__ int s_doc[NWA_];

    const int4 r0 = ((const int4*)row)[t];
    const int4 r1 = ((const int4*)row)[t + TA_];

    const int v = (t >> 3) & 3;
    int4 w0 = r0, w1 = r1;
    if (v == 1)      { w0 = make_int4(r0.y, r0.x, r0.w, r0.z); w1 = make_int4(r1.y, r1.x, r1.w, r1.z); }
    else if (v == 2) { w0 = make_int4(r0.z, r0.w, r0.x, r0.y); w1 = make_int4(r1.z, r1.w, r1.x, r1.y); }
    else if (v == 3) { w0 = make_int4(r0.w, r0.z, r0.y, r0.x); w1 = make_int4(r1.w, r1.z, r1.y, r1.x); }
    ((int4*)s_row)[t] = w0;
    ((int4*)s_row)[t + TA_] = w1;
    if (t == 0) s_row[L_] = DELIM_;

    const int c0 = (r0.x == DELIM_) + (r0.y == DELIM_) + (r0.z == DELIM_) + (r0.w == DELIM_);
    const int c1 = (r1.x == DELIM_) + (r1.y == DELIM_) + (r1.z == DELIM_) + (r1.w == DELIM_);
    const int packed = c0 | (c1 << 16);

    int sv = packed;
#pragma unroll
    for (int d = 1; d < 64; d <<= 1) {
        int n = __shfl_up(sv, d, 64);
        if (lane >= d) sv += n;
    }
    if (lane == 63) s_wsum[w] = sv;
    __syncthreads();

    int woff = 0, tot = 0;
#pragma unroll
    for (int i = 0; i < NWA_; ++i) {
        const int s = s_wsum[i];
        if (i < w) woff += s;
        tot += s;
    }
    const int pre = woff + sv - packed;
    const int c0tot = tot & 0xffff;
    const int m = c0tot + (tot >> 16);
    const int off0 = pre & 0xffff;
    const int off1 = c0tot + (pre >> 16);

    if (c0 > 0 && off0 < N_ - 1) {
        int o = off0;
        const int p = 4 * t;
        if (r0.x == DELIM_) { if (o < N_ - 1) s_dpos[o] = p;     ++o; }
        if (r0.y == DELIM_) { if (o < N_ - 1) s_dpos[o] = p + 1; ++o; }
        if (r0.z == DELIM_) { if (o < N_ - 1) s_dpos[o] = p + 2; ++o; }
        if (r0.w == DELIM_) { if (o < N_ - 1) s_dpos[o] = p + 3; ++o; }
    }
    if (c1 > 0 && off1 < N_ - 1) {
        int o = off1;
        const int p = 4 * TA_ + 4 * t;
        if (r1.x == DELIM_) { if (o < N_ - 1) s_dpos[o] = p;     ++o; }
        if (r1.y == DELIM_) { if (o < N_ - 1) s_dpos[o] = p + 1; ++o; }
        if (r1.z == DELIM_) { if (o < N_ - 1) s_dpos[o] = p + 2; ++o; }
        if (r1.w == DELIM_) { if (o < N_ - 1) s_dpos[o] = p + 3; ++o; }
    }
    __syncthreads();

    if (t < N_) {
        const int k = t;
        const int mc = (m < N_ - 1) ? m : (N_ - 1);
        int start = 0, cl = 0;
        if (k <= mc) {
            start = (k == 0) ? 0 : (s_dpos[k - 1] + 1);
            const int end = (k < mc) ? s_dpos[k] : L_;
            const int size = end - start + 1;
            cl = (size <= 1) ? 0 : (size < S_ ? size : S_);
        }
        s_start[k] = start;
        s_cl[k] = cl;
    }
    __syncthreads();

    float* __restrict__ otp_b = otp + (size_t)b * N_ * S_;
    float* __restrict__ msk_b = mask + (size_t)b * N_ * S_;
    int doccnt = 0;
    const int e0 = lane << 2;
#pragma unroll
    for (int i = 0; i < (N_ / NWA_); ++i) {
        const int k = i * NWA_ + w;
        const int start = s_start[k];
        const int cl = s_cl[k];
        float4 tf = make_float4(0.f, 0.f, 0.f, 0.f);
        float4 mk = make_float4(0.f, 0.f, 0.f, 0.f);
        int len = 0;
        if (cl > 0) {
            const int cm = cl - 1;
            int t0 = s_row[sw_idx(start + (e0 + 0 <= cm ? e0 + 0 : cm))];
            int t1 = s_row[sw_idx(start + (e0 + 1 <= cm ? e0 + 1 : cm))];
            int t2 = s_row[sw_idx(start + (e0 + 2 <= cm ? e0 + 2 : cm))];
            int t3 = s_row[sw_idx(start + (e0 + 3 <= cm ? e0 + 3 : cm))];
            t0 = (e0 + 0 < cl) ? t0 : 0;
            t1 = (e0 + 1 < cl) ? t1 : 0;
            t2 = (e0 + 2 < cl) ? t2 : 0;
            t3 = (e0 + 3 < cl) ? t3 : 0;
            len += __popcll(__ballot(t0 != 0));
            len += __popcll(__ballot(t1 != 0));
            len += __popcll(__ballot(t2 != 0));
            len += __popcll(__ballot(t3 != 0));
            tf = make_float4((float)t0, (float)t1, (float)t2, (float)t3);
            mk = make_float4(e0 + 0 < len ? 1.f : 0.f, e0 + 1 < len ? 1.f : 0.f,
                             e0 + 2 < len ? 1.f : 0.f, e0 + 3 < len ? 1.f : 0.f);
        }
        ((float4*)(otp_b + (size_t)k * S_))[lane] = tf;
        ((float4*)(msk_b + (size_t)k * S_))[lane] = mk;
        doccnt += (len > 0);
    }

    if (lane == 0) s_doc[w] = doccnt;
    __syncthreads();
    if (t == 0) {
        int d = 0;
#pragma unroll
        for (int i = 0; i < NWA_; ++i) d += s_doc[i];
        len_doc[b] = (float)d;
    }
}

extern "C" void kernel_launch(void* const* d_in, const int* in_sizes, int n_in,
                              void* d_out, int out_size, void* d_ws, size_t ws_size,
                              hipStream_t stream) {
    const int* x = (const int*)d_in[0];
    float* out = (float*)d_out;

    // d_out layout (flat, return order): otp[B*N*S] | len_doc[B] | mask[B*N*S]
    float* otp = out;
    float* len_doc = out + (size_t)B_ * N_ * S_;
    float* mask = len_doc + B_;

    const size_t tbl_bytes = (size_t)B_ * N_ * sizeof(int2);
    if (d_ws != nullptr && ws_size >= tbl_bytes) {
        int2* tbl = (int2*)d_ws;
        table_kernel<<<B_, TA_, 0, stream>>>(x, tbl, len_doc);
        write_kernel<<<dim3(8, B_), TB_, 0, stream>>>(x, tbl, otp, len_doc, mask);
    } else {
        split_kernel<<<B_, TA_, 0, stream>>>(x, otp, len_doc, mask);
    }
}

// Round 4
// 142.132 us; speedup vs baseline: 1.0446x; 1.0289x over previous
//
#include <hip/hip_runtime.h>

#define B_ 512
#define L_ 8192
#define N_ 128
#define S_ 256
#define DELIM_ 5
#define T_ 1024          // 16 waves/block; 2 blocks/CU (thread-limited), 512 blocks = exactly 1 round
#define NW_ (T_ / 64)

// Single lean kernel, one block per row.
// Phase 1: coalesced int4 row read -> registers only; packed block scan ->
//          ordered delimiter positions s_dpos (the only LDS of note, ~512 B).
// Phase 2: wave w handles sentence k = i*NW_+w; start/cl derived INLINE from
//          s_dpos + m (no chunk-table phase, one less barrier). Tokens
//          gathered straight from global x — the row was read by THIS block
//          in phase 1, so it hits the same-XCD L2. Element layout e=64j+lane:
//          every load/store is a coalesced 256 B dword op (width and nt both
//          measured neutral in R1/R2 — plain dword keeps the clean layout).
//          ballot+popc for len_sent; LDS reduce for len_doc. No atomics.
// LDS total ~640 B (vs 33 KB before) -> no LDS occupancy constraint.
__global__ __launch_bounds__(T_, 8) void split_kernel(const int* __restrict__ x,
                                                      float* __restrict__ otp,
                                                      float* __restrict__ len_doc,
                                                      float* __restrict__ mask) {
    const int b = blockIdx.x;
    const int t = threadIdx.x;
    const int lane = t & 63;
    const int w = t >> 6;
    const int* __restrict__ row = x + (size_t)b * L_;

    __shared__ int s_wsum[NW_];
    __shared__ int s_dpos[N_ - 1];  // first 127 delimiter positions (tail merge)
    __shared__ int s_doc[NW_];

    // ---- phase 1a: coalesced int4 loads; count delims ----
    const int4 r0 = ((const int4*)row)[t];        // tokens [4t, 4t+4)
    const int4 r1 = ((const int4*)row)[t + T_];   // tokens [4096+4t, ...)

    const int c0 = (r0.x == DELIM_) + (r0.y == DELIM_) + (r0.z == DELIM_) + (r0.w == DELIM_);
    const int c1 = (r1.x == DELIM_) + (r1.y == DELIM_) + (r1.z == DELIM_) + (r1.w == DELIM_);
    const int packed = c0 | (c1 << 16);

    // wave inclusive scan of packed counts
    int sv = packed;
#pragma unroll
    for (int d = 1; d < 64; d <<= 1) {
        int n = __shfl_up(sv, d, 64);
        if (lane >= d) sv += n;
    }
    if (lane == 63) s_wsum[w] = sv;
    __syncthreads();                               // barrier 1

    int woff = 0, tot = 0;
#pragma unroll
    for (int i = 0; i < NW_; ++i) {
        const int s = s_wsum[i];
        if (i < w) woff += s;
        tot += s;
    }
    const int pre = woff + sv - packed;         // exclusive prefix (packed)
    const int c0tot = tot & 0xffff;             // total delims in first half
    const int m = c0tot + (tot >> 16);          // total delims in row
    const int off0 = pre & 0xffff;
    const int off1 = c0tot + (pre >> 16);

    // ---- phase 1b: emit ordered delimiter positions from registers ----
    if (c0 > 0 && off0 < N_ - 1) {
        int o = off0;
        const int p = 4 * t;
        if (r0.x == DELIM_) { if (o < N_ - 1) s_dpos[o] = p;     ++o; }
        if (r0.y == DELIM_) { if (o < N_ - 1) s_dpos[o] = p + 1; ++o; }
        if (r0.z == DELIM_) { if (o < N_ - 1) s_dpos[o] = p + 2; ++o; }
        if (r0.w == DELIM_) { if (o < N_ - 1) s_dpos[o] = p + 3; ++o; }
    }
    if (c1 > 0 && off1 < N_ - 1) {
        int o = off1;
        const int p = 4 * T_ + 4 * t;
        if (r1.x == DELIM_) { if (o < N_ - 1) s_dpos[o] = p;     ++o; }
        if (r1.y == DELIM_) { if (o < N_ - 1) s_dpos[o] = p + 1; ++o; }
        if (r1.z == DELIM_) { if (o < N_ - 1) s_dpos[o] = p + 2; ++o; }
        if (r1.w == DELIM_) { if (o < N_ - 1) s_dpos[o] = p + 3; ++o; }
    }
    __syncthreads();                               // barrier 2

    // ---- phase 2: start/cl inline from s_dpos; gather global; stream out ----
    const int mc = (m < N_ - 1) ? m : (N_ - 1);    // last used chunk index
    float* __restrict__ otp_b = otp + (size_t)b * N_ * S_;
    float* __restrict__ msk_b = mask + (size_t)b * N_ * S_;
    int doccnt = 0;
#pragma unroll
    for (int i = 0; i < (N_ / NW_); ++i) {
        const int k = i * NW_ + w;
        int cl = 0, start = 0;
        if (k <= mc) {                             // wave-uniform
            start = (k == 0) ? 0 : (s_dpos[k - 1] + 1);   // LDS broadcast
            const int end = (k < mc) ? s_dpos[k] : L_;    // virtual rpad[L]=DELIM
            const int size = end - start + 1;             // delim belongs to chunk
            cl = (size <= 1) ? 0 : (size < S_ ? size : S_);  // lone delim -> PAD
        }
        int t0 = 0, t1 = 0, t2 = 0, t3 = 0;
        int len = 0;
        if (cl > 0) {                              // wave-uniform skip
            // branchless clamped gather; virtual trailing delimiter at idx==L_
            {
                const int idx = start + lane;
                int v0 = row[idx < L_ ? idx : L_ - 1];
                v0 = (idx == L_) ? DELIM_ : v0;
                t0 = (lane < cl) ? v0 : 0;
            }
            {
                const int idx = start + 64 + lane;
                int v1 = row[idx < L_ ? idx : L_ - 1];
                v1 = (idx == L_) ? DELIM_ : v1;
                t1 = (64 + lane < cl) ? v1 : 0;
            }
            {
                const int idx = start + 128 + lane;
                int v2 = row[idx < L_ ? idx : L_ - 1];
                v2 = (idx == L_) ? DELIM_ : v2;
                t2 = (128 + lane < cl) ? v2 : 0;
            }
            {
                const int idx = start + 192 + lane;
                int v3 = row[idx < L_ ? idx : L_ - 1];
                v3 = (idx == L_) ? DELIM_ : v3;
                t3 = (192 + lane < cl) ? v3 : 0;
            }
            len += __popcll(__ballot(t0 != 0));    // wave-uniform nonzero count
            len += __popcll(__ballot(t1 != 0));
            len += __popcll(__ballot(t2 != 0));
            len += __popcll(__ballot(t3 != 0));
        }
        // stores unconditional: cl==0 sentences must emit zeros too
        otp_b[(size_t)k * S_ + lane]       = (float)t0;
        otp_b[(size_t)k * S_ + lane + 64]  = (float)t1;
        otp_b[(size_t)k * S_ + lane + 128] = (float)t2;
        otp_b[(size_t)k * S_ + lane + 192] = (float)t3;
        msk_b[(size_t)k * S_ + lane]       = (lane       < len) ? 1.0f : 0.0f;
        msk_b[(size_t)k * S_ + lane + 64]  = (lane + 64  < len) ? 1.0f : 0.0f;
        msk_b[(size_t)k * S_ + lane + 128] = (lane + 128 < len) ? 1.0f : 0.0f;
        msk_b[(size_t)k * S_ + lane + 192] = (lane + 192 < len) ? 1.0f : 0.0f;
        doccnt += (len > 0);
    }

    // ---- len_doc: one LDS reduction per block, no atomics ----
    if (lane == 0) s_doc[w] = doccnt;
    __syncthreads();                               // barrier 3
    if (t == 0) {
        int d = 0;
#pragma unroll
        for (int i = 0; i < NW_; ++i) d += s_doc[i];
        len_doc[b] = (float)d;
    }
}

extern "C" void kernel_launch(void* const* d_in, const int* in_sizes, int n_in,
                              void* d_out, int out_size, void* d_ws, size_t ws_size,
                              hipStream_t stream) {
    const int* x = (const int*)d_in[0];
    float* out = (float*)d_out;

    // d_out layout (flat, return order): otp[B*N*S] | len_doc[B] | mask[B*N*S]
    float* otp = out;
    float* len_doc = out + (size_t)B_ * N_ * S_;
    float* mask = len_doc + B_;

    split_kernel<<<B_, T_, 0, stream>>>(x, otp, len_doc, mask);
}